// Round 6
// baseline (8722.036 us; speedup 1.0000x reference)
//
#include <hip/hip_runtime.h>
#include <math.h>

#define HALF _Float16
typedef _Float16 half8 __attribute__((ext_vector_type(8)));
typedef float floatx4 __attribute__((ext_vector_type(4)));

#define SPIN_MAX (1 << 14)

// ---------------- cast / prep kernels ----------------
__global__ __launch_bounds__(256) void k_cast(const float* __restrict__ s, HALF* __restrict__ d, int n) {
    int i = blockIdx.x * 256 + threadIdx.x;
    if (i < n) d[i] = (HALF)s[i];
}

// 512x512 slice out of [512,1024] (src ld 1024)
__global__ __launch_bounds__(256) void k_cast_slice(const float* __restrict__ s, HALF* __restrict__ d, int off) {
    int i = blockIdx.x * 256 + threadIdx.x;  // 262144
    int r = i >> 9, c = i & 511;
    d[i] = (HALF)s[r * 1024 + off + c];
}

// d[c][r] = s[r][c], 512x512
__global__ __launch_bounds__(256) void k_transpose_cast(const float* __restrict__ s, HALF* __restrict__ d) {
    int i = blockIdx.x * 256 + threadIdx.x;
    int r = i >> 9, c = i & 511;
    d[c * 512 + r] = (HALF)s[i];
}

// bcat[j][n] = bias_j[n] + sum_k b2[k]*Wj[n][k]   (j: 0=time,1=g,2=hn)
__global__ __launch_bounds__(256) void k_fuse_bias(const float* __restrict__ b2,
    const float* __restrict__ tw, const float* __restrict__ tb,
    const float* __restrict__ gw, const float* __restrict__ gb,
    const float* __restrict__ hw, const float* __restrict__ hb,
    float* __restrict__ bcat) {
    int i = blockIdx.x * 256 + threadIdx.x;
    if (i >= 1536) return;
    int j = i >> 9, n = i & 511;
    const float* W  = (j == 0) ? tw : (j == 1 ? gw : hw);
    const float* bb = (j == 0) ? tb : (j == 1 ? gb : hb);
    float s = bb[n];
    for (int k = 0; k < 512; ++k) s += b2[k] * W[n * 512 + k];
    bcat[i] = s;
}

// reorder Ascan: out[t*4096 + blk*64 + m*8 + nl] = in[(m*1024+t)*512 + blk*8 + nl]
__global__ __launch_bounds__(256) void k_reorderA(const float* __restrict__ in, float* __restrict__ out) {
    int i = blockIdx.x * 256 + threadIdx.x;  // 4194304
    int nl = i & 7, m = (i >> 3) & 7, blk = (i >> 6) & 63, t = i >> 12;
    out[i] = in[((long long)(m << 10 | t)) * 512 + blk * 8 + nl];
}

// ---------------- generic f16 MFMA GEMM: C[m,n] = alpha*sum_k A[m,k]*Bw[n,k] + bias[n] ----------------
__global__ __launch_bounds__(256)
void k_gemm(const HALF* __restrict__ A, int lda, long long sAz,
            const HALF* __restrict__ Bw, int ldb, long long sBz,
            float* __restrict__ Cf, HALF* __restrict__ Ch, int ldc, long long sCz,
            const float* __restrict__ bias, float alpha,
            int M, int N, int K)
{
    __shared__ HALF As[64][72];
    __shared__ HALF Ws[64][72];
    const int tid = threadIdx.x;
    const int bx = blockIdx.x, by = blockIdx.y, z = blockIdx.z;
    A  += (long long)z * sAz;
    Bw += (long long)z * sBz;
    const long long coff = (long long)z * sCz;
    const int wave = tid >> 6, lane = tid & 63;
    const int wrow = (wave >> 1) * 32, wcol = (wave & 1) * 32;
    const int frow = lane & 15, fquad = lane >> 4;
    const int srow = tid >> 3, sch = (tid & 7) * 8;
    floatx4 acc[2][2] = {};
    for (int k0 = 0; k0 < K; k0 += 64) {
        uint4 a0 = *(const uint4*)(A + (long long)(by * 64 + srow) * lda + k0 + sch);
        uint4 a1 = *(const uint4*)(A + (long long)(by * 64 + srow + 32) * lda + k0 + sch);
        uint4 b0 = *(const uint4*)(Bw + (long long)(bx * 64 + srow) * ldb + k0 + sch);
        uint4 b1 = *(const uint4*)(Bw + (long long)(bx * 64 + srow + 32) * ldb + k0 + sch);
        *(uint4*)&As[srow][sch] = a0;
        *(uint4*)&As[srow + 32][sch] = a1;
        *(uint4*)&Ws[srow][sch] = b0;
        *(uint4*)&Ws[srow + 32][sch] = b1;
        __syncthreads();
        #pragma unroll
        for (int ks = 0; ks < 64; ks += 32) {
            half8 fa0 = *(const half8*)&As[wrow + frow][ks + fquad * 8];
            half8 fa1 = *(const half8*)&As[wrow + 16 + frow][ks + fquad * 8];
            half8 fb0 = *(const half8*)&Ws[wcol + frow][ks + fquad * 8];
            half8 fb1 = *(const half8*)&Ws[wcol + 16 + frow][ks + fquad * 8];
            acc[0][0] = __builtin_amdgcn_mfma_f32_16x16x32_f16(fa0, fb0, acc[0][0], 0, 0, 0);
            acc[0][1] = __builtin_amdgcn_mfma_f32_16x16x32_f16(fa0, fb1, acc[0][1], 0, 0, 0);
            acc[1][0] = __builtin_amdgcn_mfma_f32_16x16x32_f16(fa1, fb0, acc[1][0], 0, 0, 0);
            acc[1][1] = __builtin_amdgcn_mfma_f32_16x16x32_f16(fa1, fb1, acc[1][1], 0, 0, 0);
        }
        __syncthreads();
    }
    const int crow = (lane >> 4) * 4, ccol = lane & 15;
    #pragma unroll
    for (int i = 0; i < 2; ++i)
        #pragma unroll
        for (int j = 0; j < 2; ++j) {
            int gn = bx * 64 + wcol + j * 16 + ccol;
            float bv = bias ? bias[gn] : 0.0f;
            #pragma unroll
            for (int r = 0; r < 4; ++r) {
                int gm = by * 64 + wrow + i * 16 + crow + r;
                float v = acc[i][j][r] * alpha + bv;
                long long idx = coff + (long long)gm * ldc + gn;
                if (Cf) Cf[idx] = v;
                if (Ch) Ch[idx] = (HALF)v;
            }
        }
}

// ---------------- qkv split ----------------
__global__ __launch_bounds__(256) void k_qkv_split(const HALF* __restrict__ qkv,
    HALF* __restrict__ Q, HALF* __restrict__ Kt, HALF* __restrict__ VT) {
    long long i = (long long)blockIdx.x * 256 + threadIdx.x;  // 4194304
    int c = (int)(i & 511);
    long long sg = i >> 9;
    int b = (int)(sg >> 10), s = (int)(sg & 1023);
    int h = c >> 6, d = c & 63;
    const HALF* src = qkv + sg * 1536;
    long long bh = (long long)(b * 8 + h);
    long long qi = (bh * 1024 + s) * 64 + d;
    Q[qi]  = src[c];
    Kt[qi] = src[512 + c];
    VT[(bh * 64 + d) * 1024 + s] = src[1024 + c];
}

// ---------------- row softmax over 1024 f16 ----------------
__global__ __launch_bounds__(256) void k_softmax(HALF* __restrict__ P) {
    long long row = (long long)blockIdx.x * 4 + (threadIdx.x >> 6);
    int lane = threadIdx.x & 63;
    uint4* p = (uint4*)(P + row * 1024);
    union { uint4 u; HALF h[8]; } u0, u1;
    u0.u = p[lane * 2]; u1.u = p[lane * 2 + 1];
    float f[16];
    #pragma unroll
    for (int i = 0; i < 8; ++i) { f[i] = (float)u0.h[i]; f[8 + i] = (float)u1.h[i]; }
    float mx = f[0];
    #pragma unroll
    for (int i = 1; i < 16; ++i) mx = fmaxf(mx, f[i]);
    #pragma unroll
    for (int o = 32; o > 0; o >>= 1) mx = fmaxf(mx, __shfl_xor(mx, o, 64));
    float sm = 0.f;
    #pragma unroll
    for (int i = 0; i < 16; ++i) { f[i] = __expf(f[i] - mx); sm += f[i]; }
    #pragma unroll
    for (int o = 32; o > 0; o >>= 1) sm += __shfl_xor(sm, o, 64);
    float r = 1.0f / sm;
    #pragma unroll
    for (int i = 0; i < 8; ++i) { u0.h[i] = (HALF)(f[i] * r); u1.h[i] = (HALF)(f[8 + i] * r); }
    p[lane * 2] = u0.u; p[lane * 2 + 1] = u1.u;
}

// ---------------- LN(X+Y) * g + b over 512 cols ----------------
__global__ __launch_bounds__(256) void k_ln_add(const float* __restrict__ X, const float* __restrict__ Y,
    const float* __restrict__ g, const float* __restrict__ bb,
    float* __restrict__ o32, HALF* __restrict__ o16) {
    long long row = (long long)blockIdx.x * 4 + (threadIdx.x >> 6);
    int lane = threadIdx.x & 63;
    const float4* xp = (const float4*)(X + row * 512);
    const float4* yp = (const float4*)(Y + row * 512);
    float v[8];
    float s = 0.f, s2 = 0.f;
    #pragma unroll
    for (int i = 0; i < 2; ++i) {
        float4 a = xp[lane * 2 + i], c = yp[lane * 2 + i];
        float t0 = a.x + c.x, t1 = a.y + c.y, t2 = a.z + c.z, t3 = a.w + c.w;
        v[i * 4 + 0] = t0; v[i * 4 + 1] = t1; v[i * 4 + 2] = t2; v[i * 4 + 3] = t3;
        s += t0 + t1 + t2 + t3;
        s2 += t0 * t0 + t1 * t1 + t2 * t2 + t3 * t3;
    }
    #pragma unroll
    for (int o = 32; o > 0; o >>= 1) { s += __shfl_xor(s, o, 64); s2 += __shfl_xor(s2, o, 64); }
    float mean = s * (1.0f / 512.0f);
    float var = s2 * (1.0f / 512.0f) - mean * mean;
    float rstd = rsqrtf(var + 1e-5f);
    #pragma unroll
    for (int i = 0; i < 8; ++i) {
        int c = lane * 8 + i;
        float o = (v[i] - mean) * rstd * g[c] + bb[c];
        if (o32) o32[row * 512 + c] = o;
        if (o16) o16[row * 512 + c] = (HALF)o;
    }
}

// ---------------- helpers ----------------
__device__ __forceinline__ floatx4 mfma16(half8 a, half8 b, floatx4 c) {
    return __builtin_amdgcn_mfma_f32_16x16x32_f16(a, b, c, 0, 0, 0);
}
// tagged payload word: [val0:16][val1:16][spare:16][tag:16]
__device__ __forceinline__ unsigned long long pack2h_tag(float a, float b, unsigned tag) {
    union { unsigned short u; HALF h; } x0, x1;
    x0.h = (HALF)a; x1.h = (HALF)b;
    return (unsigned long long)x0.u | ((unsigned long long)x1.u << 16)
         | ((unsigned long long)tag << 48);
}
// saturation-safe fast tanh: 1 - 2/(e^{2x}+1)  (x->+inf: 1, x->-inf: -1)
__device__ __forceinline__ float fast_tanh(float x) {
    float e = __expf(2.0f * x);
    return 1.0f - 2.0f / (e + 1.0f);
}

// ---------------- persistent LTC scan: 16 blocks x 4 waves, wave-autonomous, pinned weights ----------------
// Transport = R5's proven per-thread tagged payload (system-scope relaxed u64 atomics, exact-tag
// match). Two structural changes, both off the exchange path:
//  (1) WEIGHTS PINNED IN VGPRs: R5's VGPR_Count=160 < the 256 VGPRs the weight fragments need =>
//      the compiler was re-streaming ~65KB of weights per wave per phase from L1/L2 inside the
//      loop. An opaque `asm volatile("" : "+v"(x))` pin after the pre-loop loads makes each
//      fragment asm-defined, so it cannot be rematerialized; __launch_bounds__(256,1) gives the
//      512-VGPR budget to hold them (expect VGPR_Count ~340).
//  (2) WAVE-AUTONOMOUS STAGING, ZERO BARRIERS: each wave stages the full 16KB payload into its
//      OWN LDS buffer (32 words/lane in 4 chunks of 8; coalesced global reads; LDS writes at
//      SL[lane+64k] are bank-conflict-free). No __syncthreads anywhere in the loop -> no 4-wave
//      convoy, no 64-wave lockstep amplification of stragglers.
// Safety induction now at WAVE granularity: a wave stores S@t+1 only after it personally staged
// all of T@t+1; wave v publishing T@t+1 implies v finished staging (i.e. consuming) S@t. Hence
// no S@t word is overwritten while any wave still polls/stages it, and producers stay at most
// one generation ahead (exact-tag match cannot skip). Symmetric for T. SPIN_MAX escape preserved.
__global__ __launch_bounds__(256, 1)
void k_ltc_scan(const float* __restrict__ AscanR, const HALF* __restrict__ W1hg,
                const HALF* __restrict__ Wcatg, const float* __restrict__ bcat,
                unsigned long long* __restrict__ Sbuf, unsigned long long* __restrict__ Tbuf,
                float* __restrict__ outs)
{
    __shared__ unsigned int SLu[2][4][2176];  // [phase][wave][8.5KB values+pad] = 68KB
    const int tid = threadIdx.x;
    const int wv = tid >> 6, lane = tid & 63;
    const int blk = blockIdx.x * 4 + wv;      // 16 blocks x 4 waves = 64 col-slices
    const int n0 = blk * 8;
    const int c = lane & 15, q = lane >> 4;
    const int nW = n0 + (c & 7);
    const int kq = q * 8;
    const bool valid = (q < 2) && (c < 8);
    const int pidx = blk * 16 + c * 2 + q;    // logical 4-value slot; tagged words at 2*pidx, 2*pidx+1

    // zero own LDS buffers (pad + pre-first-stage safety); wave-private, no barrier needed
    for (int k = lane; k < 2176; k += 64) { SLu[0][wv][k] = 0; SLu[1][wv][k] = 0; }

    // ---- preload weight A-fragments into registers and PIN them ----
    half8 aW1[16];
    half8 aWc[3][16];
    #pragma unroll
    for (int kb = 0; kb < 16; ++kb)
        aW1[kb] = *(const half8*)(W1hg + (long long)nW * 512 + kb * 32 + kq);
    #pragma unroll
    for (int j = 0; j < 3; ++j)
        #pragma unroll
        for (int kb = 0; kb < 16; ++kb)
            aWc[j][kb] = *(const half8*)(Wcatg + ((long long)j * 512 + nW) * 512 + kb * 32 + kq);
    floatx4 binit[3];
    #pragma unroll
    for (int j = 0; j < 3; ++j) {
        float4 bv = *(const float4*)(bcat + j * 512 + n0 + (q & 1) * 4);
        binit[j][0] = bv.x; binit[j][1] = bv.y; binit[j][2] = bv.z; binit[j][3] = bv.w;
    }
    // opaque pins: values become asm-defined => loads cannot be rematerialized in the loop
    #pragma unroll
    for (int kb = 0; kb < 16; ++kb) asm volatile("" : "+v"(aW1[kb]));
    #pragma unroll
    for (int j = 0; j < 3; ++j)
        #pragma unroll
        for (int kb = 0; kb < 16; ++kb) asm volatile("" : "+v"(aWc[j][kb]));
    #pragma unroll
    for (int j = 0; j < 3; ++j) asm volatile("" : "+v"(binit[j]));

    // wave-autonomous poll+stage of the FULL payload (2048 u64) into this wave's LDS buffer.
    // 4 chunks x 8 words/lane; per chunk: retry until all 8 tags match, then write values.
    auto stage_wait = [&](const unsigned long long* __restrict__ P, unsigned tag, unsigned int* __restrict__ SL) {
        #pragma unroll
        for (int ch = 0; ch < 4; ++ch) {
            const int base = lane + ch * 512;   // words base + 64*j, j=0..7 (coalesced per j)
            unsigned long long v[8];
            #pragma unroll
            for (int j = 0; j < 8; ++j)
                v[j] = __hip_atomic_load(P + base + 64 * j, __ATOMIC_RELAXED, __HIP_MEMORY_SCOPE_SYSTEM);
            int spin = 0;
            for (;;) {
                bool ok = true;
                #pragma unroll
                for (int j = 0; j < 8; ++j) ok &= ((unsigned)(v[j] >> 48) == tag);
                if (ok || ++spin > SPIN_MAX) break;
                #pragma unroll
                for (int j = 0; j < 8; ++j)
                    v[j] = __hip_atomic_load(P + base + 64 * j, __ATOMIC_RELAXED, __HIP_MEMORY_SCOPE_SYSTEM);
            }
            #pragma unroll
            for (int j = 0; j < 8; ++j) SL[base + 64 * j] = (unsigned)v[j];  // bank-conflict-free
        }
    };

    for (int t = 0; t < 1024; ++t) {
        // prefetch A contribution (sync-independent, cached)
        float4 aval = *(const float4*)(AscanR + (long long)t * 4096 + blk * 64 + (c & 7) * 8 + (q & 1) * 4);

        // ---- wait for + stage state S_t (this wave only) ----
        stage_wait(Sbuf, (unsigned)t, SLu[0][wv]);
        const char* SLb0 = (const char*)SLu[0][wv];

        // ---- phase1: T = tanh(W1h @ S + A), B-frags from own LDS ----
        floatx4 c1a = {0.f, 0.f, 0.f, 0.f}, c1b = {0.f, 0.f, 0.f, 0.f};
        #pragma unroll
        for (int kb = 0; kb < 16; kb += 2) {
            half8 b0 = *(const half8*)(SLb0 + kb * 512 + q * 128 + c * 16);
            half8 b1 = *(const half8*)(SLb0 + (kb + 1) * 512 + q * 128 + c * 16);
            c1a = mfma16(aW1[kb],     b0, c1a);
            c1b = mfma16(aW1[kb + 1], b1, c1b);
        }
        floatx4 c1 = c1a + c1b;
        float tv0 = fast_tanh(c1[0] + aval.x);
        float tv1 = fast_tanh(c1[1] + aval.y);
        float tv2 = fast_tanh(c1[2] + aval.z);
        float tv3 = fast_tanh(c1[3] + aval.w);
        if (valid) {
            __hip_atomic_store(Tbuf + pidx * 2,     pack2h_tag(tv0, tv1, (unsigned)(t + 1)),
                               __ATOMIC_RELAXED, __HIP_MEMORY_SCOPE_SYSTEM);
            __hip_atomic_store(Tbuf + pidx * 2 + 1, pack2h_tag(tv2, tv3, (unsigned)(t + 1)),
                               __ATOMIC_RELAXED, __HIP_MEMORY_SCOPE_SYSTEM);
        }

        // ---- wait for + stage full T (this wave only) ----
        stage_wait(Tbuf, (unsigned)(t + 1), SLu[1][wv]);
        const char* SLb1 = (const char*)SLu[1][wv];

        // ---- phase2: 3 heads from T (own LDS), then gates ----
        floatx4 c2_0 = binit[0], c2_1 = binit[1], c2_2 = binit[2];
        #pragma unroll
        for (int kb = 0; kb < 16; ++kb) {
            half8 bT = *(const half8*)(SLb1 + kb * 512 + q * 128 + c * 16);
            c2_0 = mfma16(aWc[0][kb], bT, c2_0);
            c2_1 = mfma16(aWc[1][kb], bT, c2_1);
            c2_2 = mfma16(aWc[2][kb], bT, c2_2);
        }
        float sn[4];
        const float tf = (float)t;
        #pragma unroll
        for (int r = 0; r < 4; ++r) {
            float f = 1.0f / (1.0f + __expf(-c2_0[r]));
            float gate = 1.0f / (1.0f + __expf(f * tf));   // sigmoid(-f*t)
            sn[r] = gate * c2_1[r] + (1.0f - gate) * c2_2[r];
        }
        if (valid) {
            __hip_atomic_store(Sbuf + pidx * 2,     pack2h_tag(sn[0], sn[1], (unsigned)(t + 1)),
                               __ATOMIC_RELAXED, __HIP_MEMORY_SCOPE_SYSTEM);
            __hip_atomic_store(Sbuf + pidx * 2 + 1, pack2h_tag(sn[2], sn[3], (unsigned)(t + 1)),
                               __ATOMIC_RELAXED, __HIP_MEMORY_SCOPE_SYSTEM);
            // outs store: plain writeback, flushed at kernel end (off the critical path)
            float4 ov; ov.x = sn[0]; ov.y = sn[1]; ov.z = sn[2]; ov.w = sn[3];
            *(float4*)(outs + ((long long)(c << 10 | t)) * 512 + n0 + q * 4) = ov;
        }
    }
}

// ---------------- host orchestration ----------------
extern "C" void kernel_launch(void* const* d_in, const int* in_sizes, int n_in,
                              void* d_out, int out_size, void* d_ws, size_t ws_size,
                              hipStream_t stream) {
    (void)in_sizes; (void)n_in; (void)out_size; (void)ws_size;
    const float* x       = (const float*)d_in[0];
    const float* w_in_f  = (const float*)d_in[1];
    const float* b_in    = (const float*)d_in[2];
    const float* w_qkv_f = (const float*)d_in[3];
    const float* b_qkv   = (const float*)d_in[4];
    const float* w_ao_f  = (const float*)d_in[5];
    const float* b_ao    = (const float*)d_in[6];
    const float* w1_f    = (const float*)d_in[7];
    const float* b1      = (const float*)d_in[8];
    const float* w2_f    = (const float*)d_in[9];
    const float* b2      = (const float*)d_in[10];
    const float* tw_f    = (const float*)d_in[11];
    const float* tb      = (const float*)d_in[12];
    const float* gw_f    = (const float*)d_in[13];
    const float* gb      = (const float*)d_in[14];
    const float* hw_f    = (const float*)d_in[15];
    const float* hb      = (const float*)d_in[16];
    const float* n1g     = (const float*)d_in[17];
    const float* n1b     = (const float*)d_in[18];
    const float* n2g     = (const float*)d_in[19];
    const float* n2b     = (const float*)d_in[20];
    const float* w_out_f = (const float*)d_in[21];
    const float* b_out   = (const float*)d_in[22];
    float* out = (float*)d_out;

    char* p = (char*)d_ws;
    auto alloc = [&](size_t n) { char* r = p; p += (n + 255) & ~(size_t)255; return r; };
    HALF* w_in   = (HALF*)alloc(512 * 512 * 2);
    HALF* w_qkv  = (HALF*)alloc(1536 * 512 * 2);
    HALF* w_ao   = (HALF*)alloc(512 * 512 * 2);
    HALF* w_out  = (HALF*)alloc(512 * 512 * 2);
    HALF* w_time = (HALF*)alloc(512 * 512 * 2);
    HALF* w_g    = (HALF*)alloc(512 * 512 * 2);
    HALF* w_hn   = (HALF*)alloc(512 * 512 * 2);
    HALF* W2T    = (HALF*)alloc(512 * 512 * 2);
    HALF* W1x    = (HALF*)alloc(512 * 512 * 2);
    HALF* W1h    = (HALF*)alloc(512 * 512 * 2);
    HALF* Wcat   = (HALF*)alloc(3 * 512 * 512 * 2);
    float* bcat  = (float*)alloc(3 * 512 * 4 + 64);
    HALF* xb     = (HALF*)alloc(8192ll * 512 * 2);     // -> ctx16 later
    float* h32   = (float*)alloc(8192ll * 512 * 4);    // -> Ascan32 later
    HALF* h16    = (HALF*)alloc(8192ll * 512 * 2);     // -> y16 later
    HALF* qkv16  = (HALF*)alloc(8192ll * 1536 * 2);    // -> attnproj32, then outs32
    HALF* Q16    = (HALF*)alloc(8192ll * 512 * 2);
    HALF* K16    = (HALF*)alloc(8192ll * 512 * 2);     // K16+VT16 -> AscanR (16MB)
    HALF* VT16   = (HALF*)alloc(8192ll * 512 * 2);     // -> hatt16
    HALF* P16    = (HALF*)alloc(8ll * 1024 * 1024 * 2);// scores chunk; -> hatt32
    unsigned long long* Sbuf = (unsigned long long*)alloc(16384 + 256);  // tagged payload (2048 u64) + pad
    unsigned long long* Tbuf = (unsigned long long*)alloc(16384 + 256);

    // aliases over dead buffers
    HALF*  ctx16      = xb;
    float* attnproj32 = (float*)qkv16;
    float* hatt32     = (float*)P16;
    HALF*  hatt16     = VT16;
    float* Ascan32    = h32;
    float* AscanR     = (float*)K16;      // 16MB spanning K16+VT16 (both dead by then)
    float* outs32     = (float*)qkv16;    // 16MB, dead after ln1
    HALF*  y16        = h16;

    // zero tagged payload buffers (tag 0 == initial S generation, data 0 == initial state)
    hipMemsetAsync(Sbuf, 0, (16384 + 256) * 2, stream);

    // weight casts
    k_cast<<<1024, 256, 0, stream>>>(w_in_f, w_in, 262144);
    k_cast<<<3072, 256, 0, stream>>>(w_qkv_f, w_qkv, 786432);
    k_cast<<<1024, 256, 0, stream>>>(w_ao_f, w_ao, 262144);
    k_cast<<<1024, 256, 0, stream>>>(w_out_f, w_out, 262144);
    k_cast<<<1024, 256, 0, stream>>>(tw_f, w_time, 262144);
    k_cast<<<1024, 256, 0, stream>>>(gw_f, w_g, 262144);
    k_cast<<<1024, 256, 0, stream>>>(hw_f, w_hn, 262144);
    k_cast<<<16384, 256, 0, stream>>>(x, xb, 4194304);
    k_transpose_cast<<<1024, 256, 0, stream>>>(w2_f, W2T);
    k_cast_slice<<<1024, 256, 0, stream>>>(w1_f, W1x, 0);
    k_cast_slice<<<1024, 256, 0, stream>>>(w1_f, W1h, 512);
    k_fuse_bias<<<6, 256, 0, stream>>>(b2, tw_f, tb, gw_f, gb, hw_f, hb, bcat);

    // fold ltc_w2 into the three heads: Wcat[j] = Wj @ ltc_w2
    dim3 g88(8, 8, 1);
    k_gemm<<<g88, 256, 0, stream>>>(w_time, 512, 0, W2T, 512, 0, nullptr, Wcat,          512, 0, nullptr, 1.0f, 512, 512, 512);
    k_gemm<<<g88, 256, 0, stream>>>(w_g,    512, 0, W2T, 512, 0, nullptr, Wcat + 262144, 512, 0, nullptr, 1.0f, 512, 512, 512);
    k_gemm<<<g88, 256, 0, stream>>>(w_hn,   512, 0, W2T, 512, 0, nullptr, Wcat + 524288, 512, 0, nullptr, 1.0f, 512, 512, 512);

    // h = x @ in_proj_w^T + b
    dim3 gh(8, 128, 1);
    k_gemm<<<gh, 256, 0, stream>>>(xb, 512, 0, w_in, 512, 0, h32, h16, 512, 0, b_in, 1.0f, 8192, 512, 512);
    // qkv
    dim3 gq(24, 128, 1);
    k_gemm<<<gq, 256, 0, stream>>>(h16, 512, 0, w_qkv, 512, 0, nullptr, qkv16, 1536, 0, b_qkv, 1.0f, 8192, 1536, 512);
    k_qkv_split<<<16384, 256, 0, stream>>>(qkv16, Q16, K16, VT16);

    // attention, one batch (8 heads) at a time
    for (int c = 0; c < 8; ++c) {
        dim3 gs(16, 16, 8);
        k_gemm<<<gs, 256, 0, stream>>>(Q16 + c * 524288, 64, 65536, K16 + c * 524288, 64, 65536,
                                       nullptr, P16, 1024, 1048576, nullptr, 0.125f, 1024, 1024, 64);
        k_softmax<<<2048, 256, 0, stream>>>(P16);
        dim3 gc(1, 16, 8);
        k_gemm<<<gc, 256, 0, stream>>>(P16, 1024, 1048576, VT16 + c * 524288, 1024, 65536,
                                       nullptr, ctx16 + (long long)c * 524288, 512, 64, nullptr, 1.0f, 1024, 64, 1024);
    }

    // attn out proj + LN1  (attnproj32 aliases qkv16; outs32 reuses it afterwards)
    k_gemm<<<gh, 256, 0, stream>>>(ctx16, 512, 0, w_ao, 512, 0, attnproj32, nullptr, 512, 0, b_ao, 1.0f, 8192, 512, 512);
    k_ln_add<<<2048, 256, 0, stream>>>(h32, attnproj32, n1g, n1b, hatt32, hatt16);

    // scan precompute: Ascan = h_att @ W1x^T + b1, then reorder for per-block contiguity
    k_gemm<<<gh, 256, 0, stream>>>(hatt16, 512, 0, W1x, 512, 0, Ascan32, nullptr, 512, 0, b1, 1.0f, 8192, 512, 512);
    k_reorderA<<<16384, 256, 0, stream>>>(Ascan32, AscanR);

    // sequential LTC scan: 16 blocks x 4 waves, wave-autonomous tagged protocol, pinned weights
    k_ltc_scan<<<16, 256, 0, stream>>>(AscanR, W1h, Wcat, bcat, Sbuf, Tbuf, outs32);

    // LN2 + final projection
    k_ln_add<<<2048, 256, 0, stream>>>(outs32, hatt32, n2g, n2b, nullptr, y16);
    k_gemm<<<gh, 256, 0, stream>>>(y16, 512, 0, w_out, 512, 0, out, nullptr, 512, 0, b_out, 1.0f, 8192, 512, 512);
}

// Round 7
// 5843.160 us; speedup vs baseline: 1.4927x; 1.4927x over previous
//
#include <hip/hip_runtime.h>
#include <math.h>

#define HALF _Float16
typedef _Float16 half8 __attribute__((ext_vector_type(8)));
typedef float floatx4 __attribute__((ext_vector_type(4)));

#define SPIN_MAX (1 << 14)

// ---------------- cast / prep kernels ----------------
__global__ __launch_bounds__(256) void k_cast(const float* __restrict__ s, HALF* __restrict__ d, int n) {
    int i = blockIdx.x * 256 + threadIdx.x;
    if (i < n) d[i] = (HALF)s[i];
}

// 512x512 slice out of [512,1024] (src ld 1024)
__global__ __launch_bounds__(256) void k_cast_slice(const float* __restrict__ s, HALF* __restrict__ d, int off) {
    int i = blockIdx.x * 256 + threadIdx.x;  // 262144
    int r = i >> 9, c = i & 511;
    d[i] = (HALF)s[r * 1024 + off + c];
}

// d[c][r] = s[r][c], 512x512
__global__ __launch_bounds__(256) void k_transpose_cast(const float* __restrict__ s, HALF* __restrict__ d) {
    int i = blockIdx.x * 256 + threadIdx.x;
    int r = i >> 9, c = i & 511;
    d[c * 512 + r] = (HALF)s[i];
}

// bcat[j][n] = bias_j[n] + sum_k b2[k]*Wj[n][k]   (j: 0=time,1=g,2=hn)
__global__ __launch_bounds__(256) void k_fuse_bias(const float* __restrict__ b2,
    const float* __restrict__ tw, const float* __restrict__ tb,
    const float* __restrict__ gw, const float* __restrict__ gb,
    const float* __restrict__ hw, const float* __restrict__ hb,
    float* __restrict__ bcat) {
    int i = blockIdx.x * 256 + threadIdx.x;
    if (i >= 1536) return;
    int j = i >> 9, n = i & 511;
    const float* W  = (j == 0) ? tw : (j == 1 ? gw : hw);
    const float* bb = (j == 0) ? tb : (j == 1 ? gb : hb);
    float s = bb[n];
    for (int k = 0; k < 512; ++k) s += b2[k] * W[n * 512 + k];
    bcat[i] = s;
}

// reorder Ascan: out[t*4096 + blk*64 + m*8 + nl] = in[(m*1024+t)*512 + blk*8 + nl]
__global__ __launch_bounds__(256) void k_reorderA(const float* __restrict__ in, float* __restrict__ out) {
    int i = blockIdx.x * 256 + threadIdx.x;  // 4194304
    int nl = i & 7, m = (i >> 3) & 7, blk = (i >> 6) & 63, t = i >> 12;
    out[i] = in[((long long)(m << 10 | t)) * 512 + blk * 8 + nl];
}

// ---------------- generic f16 MFMA GEMM: C[m,n] = alpha*sum_k A[m,k]*Bw[n,k] + bias[n] ----------------
__global__ __launch_bounds__(256)
void k_gemm(const HALF* __restrict__ A, int lda, long long sAz,
            const HALF* __restrict__ Bw, int ldb, long long sBz,
            float* __restrict__ Cf, HALF* __restrict__ Ch, int ldc, long long sCz,
            const float* __restrict__ bias, float alpha,
            int M, int N, int K)
{
    __shared__ HALF As[64][72];
    __shared__ HALF Ws[64][72];
    const int tid = threadIdx.x;
    const int bx = blockIdx.x, by = blockIdx.y, z = blockIdx.z;
    A  += (long long)z * sAz;
    Bw += (long long)z * sBz;
    const long long coff = (long long)z * sCz;
    const int wave = tid >> 6, lane = tid & 63;
    const int wrow = (wave >> 1) * 32, wcol = (wave & 1) * 32;
    const int frow = lane & 15, fquad = lane >> 4;
    const int srow = tid >> 3, sch = (tid & 7) * 8;
    floatx4 acc[2][2] = {};
    for (int k0 = 0; k0 < K; k0 += 64) {
        uint4 a0 = *(const uint4*)(A + (long long)(by * 64 + srow) * lda + k0 + sch);
        uint4 a1 = *(const uint4*)(A + (long long)(by * 64 + srow + 32) * lda + k0 + sch);
        uint4 b0 = *(const uint4*)(Bw + (long long)(bx * 64 + srow) * ldb + k0 + sch);
        uint4 b1 = *(const uint4*)(Bw + (long long)(bx * 64 + srow + 32) * ldb + k0 + sch);
        *(uint4*)&As[srow][sch] = a0;
        *(uint4*)&As[srow + 32][sch] = a1;
        *(uint4*)&Ws[srow][sch] = b0;
        *(uint4*)&Ws[srow + 32][sch] = b1;
        __syncthreads();
        #pragma unroll
        for (int ks = 0; ks < 64; ks += 32) {
            half8 fa0 = *(const half8*)&As[wrow + frow][ks + fquad * 8];
            half8 fa1 = *(const half8*)&As[wrow + 16 + frow][ks + fquad * 8];
            half8 fb0 = *(const half8*)&Ws[wcol + frow][ks + fquad * 8];
            half8 fb1 = *(const half8*)&Ws[wcol + 16 + frow][ks + fquad * 8];
            acc[0][0] = __builtin_amdgcn_mfma_f32_16x16x32_f16(fa0, fb0, acc[0][0], 0, 0, 0);
            acc[0][1] = __builtin_amdgcn_mfma_f32_16x16x32_f16(fa0, fb1, acc[0][1], 0, 0, 0);
            acc[1][0] = __builtin_amdgcn_mfma_f32_16x16x32_f16(fa1, fb0, acc[1][0], 0, 0, 0);
            acc[1][1] = __builtin_amdgcn_mfma_f32_16x16x32_f16(fa1, fb1, acc[1][1], 0, 0, 0);
        }
        __syncthreads();
    }
    const int crow = (lane >> 4) * 4, ccol = lane & 15;
    #pragma unroll
    for (int i = 0; i < 2; ++i)
        #pragma unroll
        for (int j = 0; j < 2; ++j) {
            int gn = bx * 64 + wcol + j * 16 + ccol;
            float bv = bias ? bias[gn] : 0.0f;
            #pragma unroll
            for (int r = 0; r < 4; ++r) {
                int gm = by * 64 + wrow + i * 16 + crow + r;
                float v = acc[i][j][r] * alpha + bv;
                long long idx = coff + (long long)gm * ldc + gn;
                if (Cf) Cf[idx] = v;
                if (Ch) Ch[idx] = (HALF)v;
            }
        }
}

// ---------------- qkv split ----------------
__global__ __launch_bounds__(256) void k_qkv_split(const HALF* __restrict__ qkv,
    HALF* __restrict__ Q, HALF* __restrict__ Kt, HALF* __restrict__ VT) {
    long long i = (long long)blockIdx.x * 256 + threadIdx.x;  // 4194304
    int c = (int)(i & 511);
    long long sg = i >> 9;
    int b = (int)(sg >> 10), s = (int)(sg & 1023);
    int h = c >> 6, d = c & 63;
    const HALF* src = qkv + sg * 1536;
    long long bh = (long long)(b * 8 + h);
    long long qi = (bh * 1024 + s) * 64 + d;
    Q[qi]  = src[c];
    Kt[qi] = src[512 + c];
    VT[(bh * 64 + d) * 1024 + s] = src[1024 + c];
}

// ---------------- row softmax over 1024 f16 ----------------
__global__ __launch_bounds__(256) void k_softmax(HALF* __restrict__ P) {
    long long row = (long long)blockIdx.x * 4 + (threadIdx.x >> 6);
    int lane = threadIdx.x & 63;
    uint4* p = (uint4*)(P + row * 1024);
    union { uint4 u; HALF h[8]; } u0, u1;
    u0.u = p[lane * 2]; u1.u = p[lane * 2 + 1];
    float f[16];
    #pragma unroll
    for (int i = 0; i < 8; ++i) { f[i] = (float)u0.h[i]; f[8 + i] = (float)u1.h[i]; }
    float mx = f[0];
    #pragma unroll
    for (int i = 1; i < 16; ++i) mx = fmaxf(mx, f[i]);
    #pragma unroll
    for (int o = 32; o > 0; o >>= 1) mx = fmaxf(mx, __shfl_xor(mx, o, 64));
    float sm = 0.f;
    #pragma unroll
    for (int i = 0; i < 16; ++i) { f[i] = __expf(f[i] - mx); sm += f[i]; }
    #pragma unroll
    for (int o = 32; o > 0; o >>= 1) sm += __shfl_xor(sm, o, 64);
    float r = 1.0f / sm;
    #pragma unroll
    for (int i = 0; i < 8; ++i) { u0.h[i] = (HALF)(f[i] * r); u1.h[i] = (HALF)(f[8 + i] * r); }
    p[lane * 2] = u0.u; p[lane * 2 + 1] = u1.u;
}

// ---------------- LN(X+Y) * g + b over 512 cols ----------------
__global__ __launch_bounds__(256) void k_ln_add(const float* __restrict__ X, const float* __restrict__ Y,
    const float* __restrict__ g, const float* __restrict__ bb,
    float* __restrict__ o32, HALF* __restrict__ o16) {
    long long row = (long long)blockIdx.x * 4 + (threadIdx.x >> 6);
    int lane = threadIdx.x & 63;
    const float4* xp = (const float4*)(X + row * 512);
    const float4* yp = (const float4*)(Y + row * 512);
    float v[8];
    float s = 0.f, s2 = 0.f;
    #pragma unroll
    for (int i = 0; i < 2; ++i) {
        float4 a = xp[lane * 2 + i], c = yp[lane * 2 + i];
        float t0 = a.x + c.x, t1 = a.y + c.y, t2 = a.z + c.z, t3 = a.w + c.w;
        v[i * 4 + 0] = t0; v[i * 4 + 1] = t1; v[i * 4 + 2] = t2; v[i * 4 + 3] = t3;
        s += t0 + t1 + t2 + t3;
        s2 += t0 * t0 + t1 * t1 + t2 * t2 + t3 * t3;
    }
    #pragma unroll
    for (int o = 32; o > 0; o >>= 1) { s += __shfl_xor(s, o, 64); s2 += __shfl_xor(s2, o, 64); }
    float mean = s * (1.0f / 512.0f);
    float var = s2 * (1.0f / 512.0f) - mean * mean;
    float rstd = rsqrtf(var + 1e-5f);
    #pragma unroll
    for (int i = 0; i < 8; ++i) {
        int c = lane * 8 + i;
        float o = (v[i] - mean) * rstd * g[c] + bb[c];
        if (o32) o32[row * 512 + c] = o;
        if (o16) o16[row * 512 + c] = (HALF)o;
    }
}

// ---------------- helpers ----------------
__device__ __forceinline__ floatx4 mfma16(half8 a, half8 b, floatx4 c) {
    return __builtin_amdgcn_mfma_f32_16x16x32_f16(a, b, c, 0, 0, 0);
}
// tagged payload word: [val0:16][val1:16][spare:16][tag:16]
__device__ __forceinline__ unsigned long long pack2h_tag(float a, float b, unsigned tag) {
    union { unsigned short u; HALF h; } x0, x1;
    x0.h = (HALF)a; x1.h = (HALF)b;
    return (unsigned long long)x0.u | ((unsigned long long)x1.u << 16)
         | ((unsigned long long)tag << 48);
}
// saturation-safe fast tanh: 1 - 2/(e^{2x}+1)  (x->+inf: 1, x->-inf: -1)
__device__ __forceinline__ float fast_tanh(float x) {
    float e = __expf(2.0f * x);
    return 1.0f - 2.0f / (e + 1.0f);
}

// ---------------- persistent LTC scan: 8 blocks x 4 waves, dedup 16-col slices ----------------
// Transport = R5's proven per-thread tagged payload (system-scope relaxed u64 atomics, exact-tag
// match, one barrier per stage). Structural change: the MFMA layout's M and N dims are now FULLY
// used. Old: wave owned 8 n-cols duplicated across 16 lanes (c&7) and kept only q<2 rows -> 25%
// MFMA efficiency and 64 slices (16 blocks). New: wave owns 16 DISTINCT n-cols (A-row c -> n0+c,
// all q rows valid) -> 32 slices -> 8 BLOCKS in the all-to-all (half the sync degree), and
// GPU-wide MFMA work halves. Per-lane register cost unchanged (fragments were duplicated before).
// Verified mapping (derived from the working kernel's producer/consumer algebra):
//   producer lane (c= batch <8, q=0..3) owns n = n0 + q*4 + r; payload u64 word
//   w = slice*64 + c*8 + q*2 + j holds values (sn[2j], sn[2j+1]);
//   consumer B-frag for lane (c,q), chunk kb reads LDS halves H0 = slice'*128 + c*16 + (q&1)*8,
//   slice' = kb*2 + (q>>1)  (byte addr = kb*512 + (q>>1)*256 + c*32 + (q&1)*16), giving
//   element e = S[batch c][k = kb*32 + q*8 + e] — exactly the B-layout (col=lane&15, k=(lane>>4)*8+e).
// Safety induction identical to R5 (block stores S@t+1 only after all its threads observed full
// T@t+1; producers at most one generation ahead; exact-tag match cannot skip).
__global__ __launch_bounds__(256, 1)
void k_ltc_scan(const float* __restrict__ AscanR, const HALF* __restrict__ W1hg,
                const HALF* __restrict__ Wcatg, const float* __restrict__ bcat,
                unsigned long long* __restrict__ Sbuf, unsigned long long* __restrict__ Tbuf,
                float* __restrict__ outs)
{
    __shared__ unsigned int SLu[2][2176];  // 2 x 8.5KB staged values (+pad for dup-batch lanes c>=8)
    const int tid = threadIdx.x;
    const int wv = tid >> 6, lane = tid & 63;
    const int slice = blockIdx.x * 4 + wv;    // 8 blocks x 4 waves = 32 slices x 16 cols
    const int n0 = slice * 16;
    const int c = lane & 15, q = lane >> 4;
    const bool valid = (c < 8);               // c = batch; all q rows are real now
    const int w0 = slice * 64 + c * 8 + q * 2;  // this lane's 2 payload u64 words
    const int i0 = tid * 8;                   // staging: 8 u64 words == one 64B line

    // zero both LDS buffers once (pad region for c>=8 consumer reads must be finite)
    for (int k = tid; k < 2176; k += 256) { SLu[0][k] = 0; SLu[1][k] = 0; }

    // ---- preload weight A-fragments (16 distinct rows per wave now) ----
    half8 aW1[16];
    half8 aWc[3][16];
    #pragma unroll
    for (int kb = 0; kb < 16; ++kb)
        aW1[kb] = *(const half8*)(W1hg + (long long)(n0 + c) * 512 + kb * 32 + q * 8);
    #pragma unroll
    for (int j = 0; j < 3; ++j)
        #pragma unroll
        for (int kb = 0; kb < 16; ++kb)
            aWc[j][kb] = *(const half8*)(Wcatg + ((long long)j * 512 + n0 + c) * 512 + kb * 32 + q * 8);
    floatx4 binit[3];
    #pragma unroll
    for (int j = 0; j < 3; ++j) {
        float4 bv = *(const float4*)(bcat + j * 512 + n0 + q * 4);
        binit[j][0] = bv.x; binit[j][1] = bv.y; binit[j][2] = bv.z; binit[j][3] = bv.w;
    }

    // per-thread retry until this thread's 8 words all carry `tag`, stage into SL[p], one barrier
    auto stage_wait = [&](const unsigned long long* __restrict__ P, unsigned tag, int p) {
        unsigned long long v[8];
        #pragma unroll
        for (int k = 0; k < 8; ++k)
            v[k] = __hip_atomic_load(P + i0 + k, __ATOMIC_RELAXED, __HIP_MEMORY_SCOPE_SYSTEM);
        int spin = 0;
        for (;;) {
            bool ok = true;
            #pragma unroll
            for (int k = 0; k < 8; ++k) ok &= ((unsigned)(v[k] >> 48) == tag);
            if (ok || ++spin > SPIN_MAX) break;
            #pragma unroll
            for (int k = 0; k < 8; ++k)
                v[k] = __hip_atomic_load(P + i0 + k, __ATOMIC_RELAXED, __HIP_MEMORY_SCOPE_SYSTEM);
        }
        #pragma unroll
        for (int k = 0; k < 8; ++k) SLu[p][i0 + k] = (unsigned)v[k];
        __syncthreads();
    };

    for (int t = 0; t < 1024; ++t) {
        // prefetch A contribution: A[t][batch c][n = n0 + q*4 + r]
        float4 aval = *(const float4*)(AscanR + (long long)t * 4096
                                       + slice * 128 + (q >> 1) * 64 + c * 8 + (q & 1) * 4);

        // ---- wait for + stage state S_t ----
        stage_wait(Sbuf, (unsigned)t, 0);
        const char* SLb0 = (const char*)SLu[0];

        // ---- phase1: T = tanh(W1h @ S + A), B-frags from LDS (new slice-major layout) ----
        floatx4 c1a = {0.f, 0.f, 0.f, 0.f}, c1b = {0.f, 0.f, 0.f, 0.f};
        #pragma unroll
        for (int kb = 0; kb < 16; kb += 2) {
            half8 b0 = *(const half8*)(SLb0 + kb * 512 + (q >> 1) * 256 + c * 32 + (q & 1) * 16);
            half8 b1 = *(const half8*)(SLb0 + (kb + 1) * 512 + (q >> 1) * 256 + c * 32 + (q & 1) * 16);
            c1a = mfma16(aW1[kb],     b0, c1a);
            c1b = mfma16(aW1[kb + 1], b1, c1b);
        }
        floatx4 c1 = c1a + c1b;
        float tv0 = fast_tanh(c1[0] + aval.x);
        float tv1 = fast_tanh(c1[1] + aval.y);
        float tv2 = fast_tanh(c1[2] + aval.z);
        float tv3 = fast_tanh(c1[3] + aval.w);
        if (valid) {
            __hip_atomic_store(Tbuf + w0,     pack2h_tag(tv0, tv1, (unsigned)(t + 1)),
                               __ATOMIC_RELAXED, __HIP_MEMORY_SCOPE_SYSTEM);
            __hip_atomic_store(Tbuf + w0 + 1, pack2h_tag(tv2, tv3, (unsigned)(t + 1)),
                               __ATOMIC_RELAXED, __HIP_MEMORY_SCOPE_SYSTEM);
        }

        // ---- wait for + stage full T ----
        stage_wait(Tbuf, (unsigned)(t + 1), 1);
        const char* SLb1 = (const char*)SLu[1];

        // ---- phase2: 3 heads from T (LDS), then gates ----
        floatx4 c2_0 = binit[0], c2_1 = binit[1], c2_2 = binit[2];
        #pragma unroll
        for (int kb = 0; kb < 16; ++kb) {
            half8 bT = *(const half8*)(SLb1 + kb * 512 + (q >> 1) * 256 + c * 32 + (q & 1) * 16);
            c2_0 = mfma16(aWc[0][kb], bT, c2_0);
            c2_1 = mfma16(aWc[1][kb], bT, c2_1);
            c2_2 = mfma16(aWc[2][kb], bT, c2_2);
        }
        float sn[4];
        const float tf = (float)t;
        #pragma unroll
        for (int r = 0; r < 4; ++r) {
            float f = 1.0f / (1.0f + __expf(-c2_0[r]));
            float gate = 1.0f / (1.0f + __expf(f * tf));   // sigmoid(-f*t)
            sn[r] = gate * c2_1[r] + (1.0f - gate) * c2_2[r];
        }
        if (valid) {
            __hip_atomic_store(Sbuf + w0,     pack2h_tag(sn[0], sn[1], (unsigned)(t + 1)),
                               __ATOMIC_RELAXED, __HIP_MEMORY_SCOPE_SYSTEM);
            __hip_atomic_store(Sbuf + w0 + 1, pack2h_tag(sn[2], sn[3], (unsigned)(t + 1)),
                               __ATOMIC_RELAXED, __HIP_MEMORY_SCOPE_SYSTEM);
            // outs store: plain writeback, flushed at kernel end (off the critical path)
            float4 ov; ov.x = sn[0]; ov.y = sn[1]; ov.z = sn[2]; ov.w = sn[3];
            *(float4*)(outs + ((long long)(c << 10 | t)) * 512 + n0 + q * 4) = ov;
        }
    }
}

// ---------------- host orchestration ----------------
extern "C" void kernel_launch(void* const* d_in, const int* in_sizes, int n_in,
                              void* d_out, int out_size, void* d_ws, size_t ws_size,
                              hipStream_t stream) {
    (void)in_sizes; (void)n_in; (void)out_size; (void)ws_size;
    const float* x       = (const float*)d_in[0];
    const float* w_in_f  = (const float*)d_in[1];
    const float* b_in    = (const float*)d_in[2];
    const float* w_qkv_f = (const float*)d_in[3];
    const float* b_qkv   = (const float*)d_in[4];
    const float* w_ao_f  = (const float*)d_in[5];
    const float* b_ao    = (const float*)d_in[6];
    const float* w1_f    = (const float*)d_in[7];
    const float* b1      = (const float*)d_in[8];
    const float* w2_f    = (const float*)d_in[9];
    const float* b2      = (const float*)d_in[10];
    const float* tw_f    = (const float*)d_in[11];
    const float* tb      = (const float*)d_in[12];
    const float* gw_f    = (const float*)d_in[13];
    const float* gb      = (const float*)d_in[14];
    const float* hw_f    = (const float*)d_in[15];
    const float* hb      = (const float*)d_in[16];
    const float* n1g     = (const float*)d_in[17];
    const float* n1b     = (const float*)d_in[18];
    const float* n2g     = (const float*)d_in[19];
    const float* n2b     = (const float*)d_in[20];
    const float* w_out_f = (const float*)d_in[21];
    const float* b_out   = (const float*)d_in[22];
    float* out = (float*)d_out;

    char* p = (char*)d_ws;
    auto alloc = [&](size_t n) { char* r = p; p += (n + 255) & ~(size_t)255; return r; };
    HALF* w_in   = (HALF*)alloc(512 * 512 * 2);
    HALF* w_qkv  = (HALF*)alloc(1536 * 512 * 2);
    HALF* w_ao   = (HALF*)alloc(512 * 512 * 2);
    HALF* w_out  = (HALF*)alloc(512 * 512 * 2);
    HALF* w_time = (HALF*)alloc(512 * 512 * 2);
    HALF* w_g    = (HALF*)alloc(512 * 512 * 2);
    HALF* w_hn   = (HALF*)alloc(512 * 512 * 2);
    HALF* W2T    = (HALF*)alloc(512 * 512 * 2);
    HALF* W1x    = (HALF*)alloc(512 * 512 * 2);
    HALF* W1h    = (HALF*)alloc(512 * 512 * 2);
    HALF* Wcat   = (HALF*)alloc(3 * 512 * 512 * 2);
    float* bcat  = (float*)alloc(3 * 512 * 4 + 64);
    HALF* xb     = (HALF*)alloc(8192ll * 512 * 2);     // -> ctx16 later
    float* h32   = (float*)alloc(8192ll * 512 * 4);    // -> Ascan32 later
    HALF* h16    = (HALF*)alloc(8192ll * 512 * 2);     // -> y16 later
    HALF* qkv16  = (HALF*)alloc(8192ll * 1536 * 2);    // -> attnproj32, then outs32
    HALF* Q16    = (HALF*)alloc(8192ll * 512 * 2);
    HALF* K16    = (HALF*)alloc(8192ll * 512 * 2);     // K16+VT16 -> AscanR (16MB)
    HALF* VT16   = (HALF*)alloc(8192ll * 512 * 2);     // -> hatt16
    HALF* P16    = (HALF*)alloc(8ll * 1024 * 1024 * 2);// scores chunk; -> hatt32
    unsigned long long* Sbuf = (unsigned long long*)alloc(16384 + 256);  // tagged payload (2048 u64) + pad
    unsigned long long* Tbuf = (unsigned long long*)alloc(16384 + 256);

    // aliases over dead buffers
    HALF*  ctx16      = xb;
    float* attnproj32 = (float*)qkv16;
    float* hatt32     = (float*)P16;
    HALF*  hatt16     = VT16;
    float* Ascan32    = h32;
    float* AscanR     = (float*)K16;      // 16MB spanning K16+VT16 (both dead by then)
    float* outs32     = (float*)qkv16;    // 16MB, dead after ln1
    HALF*  y16        = h16;

    // zero tagged payload buffers (tag 0 == initial S generation, data 0 == initial state)
    hipMemsetAsync(Sbuf, 0, (16384 + 256) * 2, stream);

    // weight casts
    k_cast<<<1024, 256, 0, stream>>>(w_in_f, w_in, 262144);
    k_cast<<<3072, 256, 0, stream>>>(w_qkv_f, w_qkv, 786432);
    k_cast<<<1024, 256, 0, stream>>>(w_ao_f, w_ao, 262144);
    k_cast<<<1024, 256, 0, stream>>>(w_out_f, w_out, 262144);
    k_cast<<<1024, 256, 0, stream>>>(tw_f, w_time, 262144);
    k_cast<<<1024, 256, 0, stream>>>(gw_f, w_g, 262144);
    k_cast<<<1024, 256, 0, stream>>>(hw_f, w_hn, 262144);
    k_cast<<<16384, 256, 0, stream>>>(x, xb, 4194304);
    k_transpose_cast<<<1024, 256, 0, stream>>>(w2_f, W2T);
    k_cast_slice<<<1024, 256, 0, stream>>>(w1_f, W1x, 0);
    k_cast_slice<<<1024, 256, 0, stream>>>(w1_f, W1h, 512);
    k_fuse_bias<<<6, 256, 0, stream>>>(b2, tw_f, tb, gw_f, gb, hw_f, hb, bcat);

    // fold ltc_w2 into the three heads: Wcat[j] = Wj @ ltc_w2
    dim3 g88(8, 8, 1);
    k_gemm<<<g88, 256, 0, stream>>>(w_time, 512, 0, W2T, 512, 0, nullptr, Wcat,          512, 0, nullptr, 1.0f, 512, 512, 512);
    k_gemm<<<g88, 256, 0, stream>>>(w_g,    512, 0, W2T, 512, 0, nullptr, Wcat + 262144, 512, 0, nullptr, 1.0f, 512, 512, 512);
    k_gemm<<<g88, 256, 0, stream>>>(w_hn,   512, 0, W2T, 512, 0, nullptr, Wcat + 524288, 512, 0, nullptr, 1.0f, 512, 512, 512);

    // h = x @ in_proj_w^T + b
    dim3 gh(8, 128, 1);
    k_gemm<<<gh, 256, 0, stream>>>(xb, 512, 0, w_in, 512, 0, h32, h16, 512, 0, b_in, 1.0f, 8192, 512, 512);
    // qkv
    dim3 gq(24, 128, 1);
    k_gemm<<<gq, 256, 0, stream>>>(h16, 512, 0, w_qkv, 512, 0, nullptr, qkv16, 1536, 0, b_qkv, 1.0f, 8192, 1536, 512);
    k_qkv_split<<<16384, 256, 0, stream>>>(qkv16, Q16, K16, VT16);

    // attention, one batch (8 heads) at a time
    for (int c = 0; c < 8; ++c) {
        dim3 gs(16, 16, 8);
        k_gemm<<<gs, 256, 0, stream>>>(Q16 + c * 524288, 64, 65536, K16 + c * 524288, 64, 65536,
                                       nullptr, P16, 1024, 1048576, nullptr, 0.125f, 1024, 1024, 64);
        k_softmax<<<2048, 256, 0, stream>>>(P16);
        dim3 gc(1, 16, 8);
        k_gemm<<<gc, 256, 0, stream>>>(P16, 1024, 1048576, VT16 + c * 524288, 1024, 65536,
                                       nullptr, ctx16 + (long long)c * 524288, 512, 64, nullptr, 1.0f, 1024, 64, 1024);
    }

    // attn out proj + LN1  (attnproj32 aliases qkv16; outs32 reuses it afterwards)
    k_gemm<<<gh, 256, 0, stream>>>(ctx16, 512, 0, w_ao, 512, 0, attnproj32, nullptr, 512, 0, b_ao, 1.0f, 8192, 512, 512);
    k_ln_add<<<2048, 256, 0, stream>>>(h32, attnproj32, n1g, n1b, hatt32, hatt16);

    // scan precompute: Ascan = h_att @ W1x^T + b1, then reorder for per-block contiguity
    k_gemm<<<gh, 256, 0, stream>>>(hatt16, 512, 0, W1x, 512, 0, Ascan32, nullptr, 512, 0, b1, 1.0f, 8192, 512, 512);
    k_reorderA<<<16384, 256, 0, stream>>>(Ascan32, AscanR);

    // sequential LTC scan: 8 blocks x 4 waves, dedup 16-col slices, tagged per-thread protocol
    k_ltc_scan<<<8, 256, 0, stream>>>(AscanR, W1h, Wcat, bcat, Sbuf, Tbuf, outs32);

    // LN2 + final projection
    k_ln_add<<<2048, 256, 0, stream>>>(outs32, hatt32, n2g, n2b, nullptr, y16);
    k_gemm<<<gh, 256, 0, stream>>>(y16, 512, 0, w_out, 512, 0, out, nullptr, 512, 0, b_out, 1.0f, 8192, 512, 512);
}